// Round 10
// baseline (205.361 us; speedup 1.0000x reference)
//
#include <hip/hip_runtime.h>

#define N_E 512
#define DIM 64
#define HW  4096                 // 64*64
#define NPTS (32 * HW)           // 131072 points
#define OUT_ELEMS (NPTS * DIM)   // 8388608

typedef float v2f __attribute__((ext_vector_type(2)));

// Prep: zero the loss accumulator and build e2[512] = ||emb_row||^2 in ws.
__global__ __launch_bounds__(256) void vq_prep(const float* __restrict__ emb,
                                               float* __restrict__ out,
                                               float* __restrict__ e2) {
    const int r = blockIdx.x * 256 + threadIdx.x;   // row 0..511
    if (r == 0) out[0] = 0.0f;
    const float4* rp = (const float4*)(emb + r * DIM);
    float s = 0.f;
#pragma unroll
    for (int j = 0; j < 16; ++j) {
        float4 f = rp[j];
        s = fmaf(f.x, f.x, s);
        s = fmaf(f.y, f.y, s);
        s = fmaf(f.z, f.z, s);
        s = fmaf(f.w, f.w, s);
    }
    e2[r] = s;
}

// 256 threads = 4 waves, 64 points/block, grid 2048.
// ROUND-9 LESSON: default launch_bounds let the allocator cap VGPR at 52,
// below the 64-reg z row -> hidden inner-loop reloads/spills, VALUBusy
// pinned at 56%. __launch_bounds__(256, 4): VGPR cap 512/4 = 128 -> zv
// stays resident, 4 waves/EU guaranteed.
__global__ __launch_bounds__(256, 4) void vq_main(
    const float* __restrict__ z,    // [32, 64, 64, 64] NCHW
    const float* __restrict__ emb,  // [512, 64]
    const float* __restrict__ e2g,  // [512] from vq_prep
    float* __restrict__ out)        // [0] = loss, [1..] = z_q_st NCHW
{
    const int t = threadIdx.x;
    const int q = __builtin_amdgcn_readfirstlane(t >> 6);  // wave id, SGPR
    const int l = t & 63;

    __shared__ float se2[N_E];
    __shared__ float sdm[4][64];
    __shared__ int   sim[4][64];
    __shared__ float sred[4];

    // e2 table: coalesced copy from ws
    se2[t]       = e2g[t];
    se2[256 + t] = e2g[256 + t];

    // ---- load this point's z row (coalesced per channel) ----
    const int p0 = blockIdx.x * 64;
    const int b  = p0 >> 12;
    const int hw = (p0 & 4095) + l;
    const float* zb = z + (size_t)b * DIM * HW + hw;

    v2f zv[32];
    float z2 = 0.f;
#pragma unroll
    for (int k = 0; k < 32; ++k) {
        float lo = zb[(size_t)(2 * k)     * HW];
        float hi = zb[(size_t)(2 * k + 1) * HW];
        zv[k][0] = lo; zv[k][1] = hi;
        z2 = fmaf(lo, lo, z2);
        z2 = fmaf(hi, hi, z2);
    }
    __syncthreads();

    // ---- scan this wave's 128 rows; emb loads wave-uniform (scalar pipe) ----
    const float* eb  = emb + q * 128 * DIM;
    const float* e2b = se2 + q * 128;
    float dmin = 3.4e38f;
    int   imin = 0;
#pragma unroll 2
    for (int e = 0; e < 128; ++e) {
        const float4* er4 = (const float4*)(eb + e * DIM);   // 16 x float4
        v2f a0 = {0.f,0.f}, a1 = {0.f,0.f}, a2 = {0.f,0.f}, a3 = {0.f,0.f};
#pragma unroll
        for (int j = 0; j < 8; ++j) {
            float4 f0 = er4[2 * j];
            float4 f1 = er4[2 * j + 1];
            a0 = __builtin_elementwise_fma(zv[4 * j],     (v2f){f0.x, f0.y}, a0);
            a1 = __builtin_elementwise_fma(zv[4 * j + 1], (v2f){f0.z, f0.w}, a1);
            a2 = __builtin_elementwise_fma(zv[4 * j + 2], (v2f){f1.x, f1.y}, a2);
            a3 = __builtin_elementwise_fma(zv[4 * j + 3], (v2f){f1.z, f1.w}, a3);
        }
        v2f s = (a0 + a1) + (a2 + a3);
        float dot = s[0] + s[1];
        float d = fmaf(-2.0f, dot, z2 + e2b[e]);
        if (d < dmin) { dmin = d; imin = e; }
    }
    imin += q * 128;   // ascending scan + strict < => first index within range

    // ---- combine 4 quarters per point (ascending q => global first-index) ----
    sdm[q][l] = dmin;
    sim[q][l] = imin;
    __syncthreads();
    float bd = sdm[0][l];
    int   bi = sim[0][l];
#pragma unroll
    for (int qq = 1; qq < 4; ++qq) {
        float d2 = sdm[qq][l];
        int   i2 = sim[qq][l];
        if (d2 < bd) { bd = d2; bi = i2; }
    }
    const int w = bi;   // same in all 4 waves for point l

    // ---- epilogue: wave q writes channels [16q, 16q+16) of its point ----
    float acc = 0.f;
    float* ob = out + 1 + (size_t)b * DIM * HW + hw;

#define EPI(Q)                                                          \
    {                                                                   \
        _Pragma("unroll")                                               \
        for (int j = 0; j < 16; ++j) {                                  \
            const int c = (Q) * 16 + j;                                 \
            float v = emb[w * DIM + c];                                 \
            ob[(size_t)c * HW] = v;                                     \
            float zc = (c & 1) ? zv[c >> 1][1] : zv[c >> 1][0];         \
            float d = v - zc;                                           \
            acc = fmaf(d, d, acc);                                      \
        }                                                               \
    }
    if (q == 0)      EPI(0)
    else if (q == 1) EPI(1)
    else if (q == 2) EPI(2)
    else             EPI(3)
#undef EPI

    // ---- loss reduction: wave shuffle -> LDS -> one atomic per block ----
#pragma unroll
    for (int o = 32; o > 0; o >>= 1) acc += __shfl_down(acc, o, 64);
    if (l == 0) sred[q] = acc;
    __syncthreads();
    if (t == 0) {
        float s = (sred[0] + sred[1]) + (sred[2] + sred[3]);
        atomicAdd(out, s * (1.25f / (float)OUT_ELEMS));
    }
}

extern "C" void kernel_launch(void* const* d_in, const int* in_sizes, int n_in,
                              void* d_out, int out_size, void* d_ws, size_t ws_size,
                              hipStream_t stream) {
    const float* z   = (const float*)d_in[0];
    const float* emb = (const float*)d_in[1];
    float* out = (float*)d_out;
    float* e2  = (float*)d_ws;

    vq_prep<<<2, 256, 0, stream>>>(emb, out, e2);
    vq_main<<<NPTS / 64, 256, 0, stream>>>(z, emb, e2, out);
}

// Round 11
// 204.193 us; speedup vs baseline: 1.0057x; 1.0057x over previous
//
#include <hip/hip_runtime.h>

#define N_E 512
#define DIM 64
#define HW  4096                 // 64*64
#define NPTS (32 * HW)           // 131072 points
#define OUT_ELEMS (NPTS * DIM)   // 8388608

typedef float v2f __attribute__((ext_vector_type(2)));

// Prep: zero the loss accumulator and build e2[512] = ||emb_row||^2 in ws.
__global__ __launch_bounds__(256) void vq_prep(const float* __restrict__ emb,
                                               float* __restrict__ out,
                                               float* __restrict__ e2) {
    const int r = blockIdx.x * 256 + threadIdx.x;   // row 0..511
    if (r == 0) out[0] = 0.0f;
    const float4* rp = (const float4*)(emb + r * DIM);
    float s = 0.f;
#pragma unroll
    for (int j = 0; j < 16; ++j) {
        float4 f = rp[j];
        s = fmaf(f.x, f.x, s);
        s = fmaf(f.y, f.y, s);
        s = fmaf(f.z, f.z, s);
        s = fmaf(f.w, f.w, s);
    }
    e2[r] = s;
}

// 256 threads = 4 waves, 64 points/block, grid 2048.
// ROUND-10 LESSON: even with launch_bounds(256,4) (VGPR cap 128) the
// allocator used 48 regs — the const/__restrict__ z loads are marked
// invariant => REMATERIALIZABLE, and the scheduler re-loads z inside the
// 128-row scan instead of keeping 64 regs live. Fix: pipe each zv[k]
// through asm ("+v") after loading — asm-defined values cannot be
// rematerialized, forcing the z row to stay register-resident.
__global__ __launch_bounds__(256, 4) void vq_main(
    const float* __restrict__ z,    // [32, 64, 64, 64] NCHW
    const float* __restrict__ emb,  // [512, 64]
    const float* __restrict__ e2g,  // [512] from vq_prep
    float* __restrict__ out)        // [0] = loss, [1..] = z_q_st NCHW
{
    const int t = threadIdx.x;
    const int q = __builtin_amdgcn_readfirstlane(t >> 6);  // wave id, SGPR
    const int l = t & 63;

    __shared__ float se2[N_E];
    __shared__ float sdm[4][64];
    __shared__ int   sim[4][64];
    __shared__ float sred[4];

    // e2 table: coalesced copy from ws
    se2[t]       = e2g[t];
    se2[256 + t] = e2g[256 + t];

    // ---- load this point's z row (coalesced per channel) ----
    const int p0 = blockIdx.x * 64;
    const int b  = p0 >> 12;
    const int hw = (p0 & 4095) + l;
    const float* zb = z + (size_t)b * DIM * HW + hw;

    v2f zv[32];
    float z2 = 0.f;
#pragma unroll
    for (int k = 0; k < 32; ++k) {
        float lo = zb[(size_t)(2 * k)     * HW];
        float hi = zb[(size_t)(2 * k + 1) * HW];
        zv[k][0] = lo; zv[k][1] = hi;
        z2 = fmaf(lo, lo, z2);
        z2 = fmaf(hi, hi, z2);
    }
    // Pin the z row in VGPRs (defeat invariant-load rematerialization).
#pragma unroll
    for (int k = 0; k < 32; ++k) {
        asm volatile("" : "+v"(zv[k]));
    }
    __syncthreads();

    // ---- scan this wave's 128 rows; emb loads wave-uniform (scalar pipe) ----
    const float* eb  = emb + q * 128 * DIM;
    const float* e2b = se2 + q * 128;
    float dmin = 3.4e38f;
    int   imin = 0;
#pragma unroll 2
    for (int e = 0; e < 128; ++e) {
        const float4* er4 = (const float4*)(eb + e * DIM);   // 16 x float4
        v2f a0 = {0.f,0.f}, a1 = {0.f,0.f}, a2 = {0.f,0.f}, a3 = {0.f,0.f};
#pragma unroll
        for (int j = 0; j < 8; ++j) {
            float4 f0 = er4[2 * j];
            float4 f1 = er4[2 * j + 1];
            a0 = __builtin_elementwise_fma(zv[4 * j],     (v2f){f0.x, f0.y}, a0);
            a1 = __builtin_elementwise_fma(zv[4 * j + 1], (v2f){f0.z, f0.w}, a1);
            a2 = __builtin_elementwise_fma(zv[4 * j + 2], (v2f){f1.x, f1.y}, a2);
            a3 = __builtin_elementwise_fma(zv[4 * j + 3], (v2f){f1.z, f1.w}, a3);
        }
        v2f s = (a0 + a1) + (a2 + a3);
        float dot = s[0] + s[1];
        float d = fmaf(-2.0f, dot, z2 + e2b[e]);
        if (d < dmin) { dmin = d; imin = e; }
    }
    imin += q * 128;   // ascending scan + strict < => first index within range

    // ---- combine 4 quarters per point (ascending q => global first-index) ----
    sdm[q][l] = dmin;
    sim[q][l] = imin;
    __syncthreads();
    float bd = sdm[0][l];
    int   bi = sim[0][l];
#pragma unroll
    for (int qq = 1; qq < 4; ++qq) {
        float d2 = sdm[qq][l];
        int   i2 = sim[qq][l];
        if (d2 < bd) { bd = d2; bi = i2; }
    }
    const int w = bi;   // same in all 4 waves for point l

    // ---- epilogue: wave q writes channels [16q, 16q+16) of its point ----
    float acc = 0.f;
    float* ob = out + 1 + (size_t)b * DIM * HW + hw;

#define EPI(Q)                                                          \
    {                                                                   \
        _Pragma("unroll")                                               \
        for (int j = 0; j < 16; ++j) {                                  \
            const int c = (Q) * 16 + j;                                 \
            float v = emb[w * DIM + c];                                 \
            ob[(size_t)c * HW] = v;                                     \
            float zc = (c & 1) ? zv[c >> 1][1] : zv[c >> 1][0];         \
            float d = v - zc;                                           \
            acc = fmaf(d, d, acc);                                      \
        }                                                               \
    }
    if (q == 0)      EPI(0)
    else if (q == 1) EPI(1)
    else if (q == 2) EPI(2)
    else             EPI(3)
#undef EPI

    // ---- loss reduction: wave shuffle -> LDS -> one atomic per block ----
#pragma unroll
    for (int o = 32; o > 0; o >>= 1) acc += __shfl_down(acc, o, 64);
    if (l == 0) sred[q] = acc;
    __syncthreads();
    if (t == 0) {
        float s = (sred[0] + sred[1]) + (sred[2] + sred[3]);
        atomicAdd(out, s * (1.25f / (float)OUT_ELEMS));
    }
}

extern "C" void kernel_launch(void* const* d_in, const int* in_sizes, int n_in,
                              void* d_out, int out_size, void* d_ws, size_t ws_size,
                              hipStream_t stream) {
    const float* z   = (const float*)d_in[0];
    const float* emb = (const float*)d_in[1];
    float* out = (float*)d_out;
    float* e2  = (float*)d_ws;

    vq_prep<<<2, 256, 0, stream>>>(emb, out, e2);
    vq_main<<<NPTS / 64, 256, 0, stream>>>(z, emb, e2, out);
}

// Round 12
// 135.503 us; speedup vs baseline: 1.5155x; 1.5069x over previous
//
#include <hip/hip_runtime.h>
#include <stdint.h>

#define N_E 512
#define DIM 64
#define HW  4096                 // 64*64
#define NPTS (32 * HW)           // 131072 points
#define OUT_ELEMS (NPTS * DIM)   // 8388608

typedef float  f32x4  __attribute__((ext_vector_type(4)));
typedef short  bf16x8 __attribute__((ext_vector_type(8)));

// ws layout: [0,2048) e2 fp32; [2048, 2048+64K) emb-high frags; then emb-low
#define WS_FH_OFF 2048
#define WS_FL_OFF (2048 + 65536)

__device__ __forceinline__ unsigned short f2bf_rne(float f) {
    union { float f; uint32_t u; } c; c.f = f;
    uint32_t r = c.u + 0x7FFFu + ((c.u >> 16) & 1u);
    return (unsigned short)(r >> 16);
}
__device__ __forceinline__ float bf2f(unsigned short h) {
    union { float f; uint32_t u; } c; c.u = ((uint32_t)h) << 16;
    return c.f;
}

// Prep: out[0]=0, e2[512]=||emb_row||^2 (identical op order to passing
// rounds), and pack emb into bf16 high/low A-fragments for
// mfma_f32_16x16x32_bf16: lane l of tile (n, kstep s) holds
// emb[n*16 + (l&15)][s*32 + 8*(l>>4) + j], j=0..7.
__global__ __launch_bounds__(256) void vq_prep(const float* __restrict__ emb,
                                               float* __restrict__ out,
                                               void* __restrict__ ws) {
    const int tid = blockIdx.x * 256 + threadIdx.x;
    float*  e2 = (float*)ws;
    bf16x8* fh = (bf16x8*)((char*)ws + WS_FH_OFF);
    bf16x8* fl = (bf16x8*)((char*)ws + WS_FL_OFF);
    if (tid == 0) out[0] = 0.0f;
    if (tid < 512) {
        const float4* rp = (const float4*)(emb + tid * DIM);
        float s = 0.f;
#pragma unroll
        for (int j = 0; j < 16; ++j) {
            float4 f = rp[j];
            s = fmaf(f.x, f.x, s);
            s = fmaf(f.y, f.y, s);
            s = fmaf(f.z, f.z, s);
            s = fmaf(f.w, f.w, s);
        }
        e2[tid] = s;
    }
    const int u = tid - 512;
    if (u >= 0 && u < 4096) {
        const int n = u >> 7, rem = u & 127, s = rem >> 6, l = rem & 63;
        const int entry = n * 16 + (l & 15);
        const int kb    = s * 32 + 8 * (l >> 4);
        const float* src = emb + entry * DIM + kb;
        bf16x8 hv, lv;
#pragma unroll
        for (int j = 0; j < 8; ++j) {
            float v = src[j];
            unsigned short h = f2bf_rne(v);
            float res = v - bf2f(h);
            hv[j] = (short)h;
            lv[j] = (short)f2bf_rne(res);
        }
        const int idx = (n * 2 + s) * 64 + l;
        fh[idx] = hv;
        fl[idx] = lv;
    }
}

// Main: 512 blocks x 256 thr = 2048 waves; each wave owns 64 points
// (4 point-tiles of 16). Distance GEMM via swapped-operand MFMA
// (A=emb tile, B=z points) so each lane's f32x4 holds 4 ENTRIES of ONE
// point -> per-lane argmin, cross-lane combine only at the end.
// dot = eh*zh + eh*zl + el*zh (3-term bf16 split, fp32 accum, err ~2.5e-7,
// 30x below the 1ulp@64 rounding class all passing rounds survive).
// d assembled exactly as passing rounds: fmaf(-2, dot, z2+e2).
__global__ __launch_bounds__(256, 2) void vq_main(
    const float* __restrict__ z,    // [32, 64, 64, 64] NCHW
    const float* __restrict__ emb,  // [512, 64] fp32 (epilogue gather)
    const void*  __restrict__ ws,   // e2 + fragments from vq_prep
    float* __restrict__ out)        // [0]=loss, [1..]=z_q_st NCHW
{
    const int t   = threadIdx.x;
    const int l   = t & 63;
    const int wv  = t >> 6;
    const int grp = l >> 4;       // 0..3: entry-row group / channel group
    const int col = l & 15;       // point within a 16-point tile

    const float*  e2g = (const float*)ws;
    const bf16x8* fh  = (const bf16x8*)((const char*)ws + WS_FH_OFF);
    const bf16x8* fl  = (const bf16x8*)((const char*)ws + WS_FL_OFF);

    __shared__ float se2[N_E];
    se2[t]       = e2g[t];
    se2[256 + t] = e2g[256 + t];
    __syncthreads();

    const int gw  = blockIdx.x * 4 + wv;    // wave id 0..2047
    const int p0  = gw * 64;                // 64 points, never crosses b
    const int b   = p0 >> 12;
    const int hw0 = p0 & 4095;
    const float* zb = z + (size_t)b * DIM * HW + hw0;

    // ---- load z, build bf16-split B fragments + z2 per point ----
    bf16x8 zh[4][2], zl[4][2];
    float  z2p[4];
#pragma unroll
    for (int pt = 0; pt < 4; ++pt) {
        float part = 0.f;
#pragma unroll
        for (int s = 0; s < 2; ++s) {
            bf16x8 hv, lv;
#pragma unroll
            for (int j = 0; j < 8; ++j) {
                const int ch = s * 32 + 8 * grp + j;
                float v = zb[(size_t)ch * HW + pt * 16 + col];
                part = fmaf(v, v, part);
                unsigned short h = f2bf_rne(v);
                float res = v - bf2f(h);
                hv[j] = (short)h;
                lv[j] = (short)f2bf_rne(res);
            }
            zh[pt][s] = hv;
            zl[pt][s] = lv;
        }
        part += __shfl_xor(part, 16, 64);   // combine the 4 channel groups
        part += __shfl_xor(part, 32, 64);
        z2p[pt] = part;                     // full ||z||^2 of point (pt,col)
    }

    float dmin[4] = {3.4e38f, 3.4e38f, 3.4e38f, 3.4e38f};
    int   imin[4] = {0, 0, 0, 0};

    // ---- scan 32 entry-tiles ----
#pragma unroll 1
    for (int n = 0; n < 32; ++n) {
        const bf16x8 eh0 = fh[(n * 2 + 0) * 64 + l];
        const bf16x8 eh1 = fh[(n * 2 + 1) * 64 + l];
        const bf16x8 el0 = fl[(n * 2 + 0) * 64 + l];
        const bf16x8 el1 = fl[(n * 2 + 1) * 64 + l];
        const float4 e2q = *(const float4*)(&se2[n * 16 + grp * 4]);
        const int ebase = n * 16 + grp * 4;
#pragma unroll
        for (int pt = 0; pt < 4; ++pt) {
            f32x4 acc = {0.f, 0.f, 0.f, 0.f};
            acc = __builtin_amdgcn_mfma_f32_16x16x32_bf16(eh0, zh[pt][0], acc, 0, 0, 0);
            acc = __builtin_amdgcn_mfma_f32_16x16x32_bf16(eh1, zh[pt][1], acc, 0, 0, 0);
            acc = __builtin_amdgcn_mfma_f32_16x16x32_bf16(el0, zh[pt][0], acc, 0, 0, 0);
            acc = __builtin_amdgcn_mfma_f32_16x16x32_bf16(el1, zh[pt][1], acc, 0, 0, 0);
            acc = __builtin_amdgcn_mfma_f32_16x16x32_bf16(eh0, zl[pt][0], acc, 0, 0, 0);
            acc = __builtin_amdgcn_mfma_f32_16x16x32_bf16(eh1, zl[pt][1], acc, 0, 0, 0);
            const float zz = z2p[pt];
            float d0 = fmaf(-2.f, acc[0], zz + e2q.x);
            float d1 = fmaf(-2.f, acc[1], zz + e2q.y);
            float d2 = fmaf(-2.f, acc[2], zz + e2q.z);
            float d3 = fmaf(-2.f, acc[3], zz + e2q.w);
            if (d0 < dmin[pt]) { dmin[pt] = d0; imin[pt] = ebase;     }
            if (d1 < dmin[pt]) { dmin[pt] = d1; imin[pt] = ebase + 1; }
            if (d2 < dmin[pt]) { dmin[pt] = d2; imin[pt] = ebase + 2; }
            if (d3 < dmin[pt]) { dmin[pt] = d3; imin[pt] = ebase + 3; }
        }
    }

    // ---- cross-lane combine (ties -> smaller index = global first-index) ----
#pragma unroll
    for (int pt = 0; pt < 4; ++pt) {
        float d = dmin[pt]; int i = imin[pt];
        float da = __shfl_xor(d, 16, 64); int ia = __shfl_xor(i, 16, 64);
        if (da < d || (da == d && ia < i)) { d = da; i = ia; }
        float db = __shfl_xor(d, 32, 64); int ib = __shfl_xor(i, 32, 64);
        if (db < d || (db == d && ib < i)) { d = db; i = ib; }
        dmin[pt] = d; imin[pt] = i;
    }

    // ---- loss: sum dmin once per point (group 0 only), wave-reduce ----
    float acc_l = (grp == 0) ? ((dmin[0] + dmin[1]) + (dmin[2] + dmin[3])) : 0.f;
#pragma unroll
    for (int o = 32; o > 0; o >>= 1) acc_l += __shfl_down(acc_l, o, 64);
    if (l == 0) atomicAdd(out, acc_l * (1.25f / (float)OUT_ELEMS));

    // ---- write z_q_st: lane l owns point p0+l = tile grp, col ----
    int w = imin[0];
    w = (grp == 1) ? imin[1] : w;
    w = (grp == 2) ? imin[2] : w;
    w = (grp == 3) ? imin[3] : w;
    const float4* q4 = (const float4*)(emb + w * DIM);
    float* ob = out + 1 + (size_t)b * DIM * HW + hw0 + l;
#pragma unroll
    for (int j = 0; j < 16; ++j) {
        float4 v = q4[j];
        ob[(size_t)(4 * j + 0) * HW] = v.x;
        ob[(size_t)(4 * j + 1) * HW] = v.y;
        ob[(size_t)(4 * j + 2) * HW] = v.z;
        ob[(size_t)(4 * j + 3) * HW] = v.w;
    }
}

extern "C" void kernel_launch(void* const* d_in, const int* in_sizes, int n_in,
                              void* d_out, int out_size, void* d_ws, size_t ws_size,
                              hipStream_t stream) {
    const float* z   = (const float*)d_in[0];
    const float* emb = (const float*)d_in[1];
    float* out = (float*)d_out;

    vq_prep<<<18, 256, 0, stream>>>(emb, out, d_ws);
    vq_main<<<512, 256, 0, stream>>>(z, emb, d_ws, out);
}